// Round 2
// baseline (221.166 us; speedup 1.0000x reference)
//
#include <hip/hip_runtime.h>

// Problem constants (from setup_inputs):
//   N=1024, Cin=1024, Cy=256, H=W=128, inter=256  -- all tensors fp32
#define HWDIM 128
#define NPIX  (HWDIM * HWDIM)   // 16384
#define CY    256
#define INTER 256
#define KTAPS 9
#define WEN   (CY * KTAPS)      // 2304
#define CHG   16                // channels per ch-group in k_sphi
#define NCHG  (CY / CHG)        // 16

// ---------------------------------------------------------------------------
// Algebra (why this is not a conv stack):
//   f = softmax(s_theta[:,None] + s_phi[None,:], axis=1): s_theta is constant
//   along the softmax axis -> cancels. x, theta_w, theta_b are dead.
//   s_phi bias term is a uniform shift -> also cancels. phi_b is dead.
//   s_phi = sum_cy,k we[cy,k] * ypad[...] with we[cy,k] = sum_c wp[c]*phi_w[c,cy,k]
//   z[i,:] = gamma * (g_b + g_w . q)  identical for all i, where
//   q[cy,k] = sum_hw p[h,w] * ypad[cy, h+kh-1, w+kw-1],  p = softmax(s_phi)
// ---------------------------------------------------------------------------

// K1: blocks 0..8  -> we[o] = sum_c wp[c] * phi_w[c, o]   (o in [0,2304))
//     blocks 9..72 -> zero sphi (needed: ws is poisoned, k_sphi atomicAdds)
__global__ void k_eff_phi(const float* __restrict__ phi_w,
                          const float* __restrict__ concat_w,
                          float* __restrict__ we,
                          float* __restrict__ sphi) {
    if (blockIdx.x >= 9) {
        sphi[(blockIdx.x - 9) * 256 + threadIdx.x] = 0.f;
        return;
    }
    __shared__ float wp[INTER];
    wp[threadIdx.x] = concat_w[INTER + threadIdx.x];   // w_p = concat_w[256:512]
    __syncthreads();
    int o = blockIdx.x * 256 + threadIdx.x;
    float acc = 0.f;
    for (int c = 0; c < INTER; ++c)
        acc = fmaf(wp[c], phi_w[c * WEN + o], acc);
    we[o] = acc;
}

// K2: sphi[pix] += sum over 16-channel group of 3x3 taps
// grid: 64 pixel-groups x 16 channel-groups = 1024 blocks x 256 threads
__global__ void k_sphi(const float* __restrict__ y,
                       const float* __restrict__ we,
                       float* __restrict__ sphi) {
    int pg = blockIdx.x & 63;          // pixel group
    int cg = blockIdx.x >> 6;          // channel group
    __shared__ float swe[CHG * KTAPS];
    if (threadIdx.x < CHG * KTAPS) swe[threadIdx.x] = we[cg * CHG * KTAPS + threadIdx.x];
    __syncthreads();

    int pix = pg * 256 + threadIdx.x;
    int h = pix >> 7, w = pix & 127;
    float acc = 0.f;
    for (int ci = 0; ci < CHG; ++ci) {
        const float* yc = y + (cg * CHG + ci) * NPIX;
        const float* wk = swe + ci * KTAPS;
        #pragma unroll
        for (int dh = -1; dh <= 1; ++dh) {
            int hh = h + dh;
            if ((unsigned)hh >= (unsigned)HWDIM) continue;
            const float* yr = yc + hh * HWDIM;
            #pragma unroll
            for (int dw = -1; dw <= 1; ++dw) {
                int ww = w + dw;
                if ((unsigned)ww >= (unsigned)HWDIM) continue;
                acc = fmaf(wk[(dh + 1) * 3 + (dw + 1)], yr[ww], acc);
            }
        }
    }
    atomicAdd(&sphi[pix], acc);
}

// K3: p = softmax(sphi) over all 16384 elements (single block, 1024 threads)
__global__ void k_softmax(const float* __restrict__ sphi, float* __restrict__ p) {
    __shared__ float red[1024];
    __shared__ float s_bcast;
    int tid = threadIdx.x;

    float m = -1e30f;
    for (int i = tid; i < NPIX; i += 1024) m = fmaxf(m, sphi[i]);
    red[tid] = m;
    __syncthreads();
    for (int s = 512; s > 0; s >>= 1) {
        if (tid < s) red[tid] = fmaxf(red[tid], red[tid + s]);
        __syncthreads();
    }
    if (tid == 0) s_bcast = red[0];
    __syncthreads();
    float mm = s_bcast;
    __syncthreads();

    float sum = 0.f;
    for (int i = tid; i < NPIX; i += 1024) {
        float e = expf(sphi[i] - mm);
        p[i] = e;
        sum += e;
    }
    red[tid] = sum;
    __syncthreads();
    for (int s = 512; s > 0; s >>= 1) {
        if (tid < s) red[tid] += red[tid + s];
        __syncthreads();
    }
    if (tid == 0) s_bcast = red[0];
    __syncthreads();
    float inv = 1.f / s_bcast;
    for (int i = tid; i < NPIX; i += 1024) p[i] *= inv;
}

// K4: q[cy,kh,kw] = sum_{h,w} p[h,w] * ypad[cy, h+kh-1, w+kw-1]
// grid: 256 blocks (one per cy) x 256 threads
__global__ void k_q(const float* __restrict__ y,
                    const float* __restrict__ p, float* __restrict__ q) {
    int cy = blockIdx.x;
    const float* yc = y + cy * NPIX;
    float acc[KTAPS];
    #pragma unroll
    for (int t = 0; t < KTAPS; ++t) acc[t] = 0.f;

    for (int i = threadIdx.x; i < NPIX; i += 256) {
        int h = i >> 7, w = i & 127;
        float yv = yc[i];
        #pragma unroll
        for (int kh = 0; kh < 3; ++kh) {
            int ph = h - kh + 1;                 // y[cy,h,w] pairs with p[h-kh+1, w-kw+1]
            if ((unsigned)ph >= (unsigned)HWDIM) continue;
            #pragma unroll
            for (int kw = 0; kw < 3; ++kw) {
                int pw = w - kw + 1;
                if ((unsigned)pw >= (unsigned)HWDIM) continue;
                acc[kh * 3 + kw] = fmaf(p[ph * HWDIM + pw], yv, acc[kh * 3 + kw]);
            }
        }
    }

    __shared__ float red[256];
    for (int t = 0; t < KTAPS; ++t) {
        red[threadIdx.x] = acc[t];
        __syncthreads();
        for (int s = 128; s > 0; s >>= 1) {
            if (threadIdx.x < s) red[threadIdx.x] += red[threadIdx.x + s];
            __syncthreads();
        }
        if (threadIdx.x == 0) q[cy * KTAPS + t] = red[0];
        __syncthreads();
    }
}

// K5: row[c] = gamma * (g_b[c] + sum_o g_w[c,o] * q[o])
// grid: 256 blocks x 256 threads
__global__ void k_row(const float* __restrict__ g_w,
                      const float* __restrict__ g_b,
                      const float* __restrict__ gamma,
                      const float* __restrict__ q, float* __restrict__ row) {
    __shared__ float sq[WEN];
    for (int i = threadIdx.x; i < WEN; i += 256) sq[i] = q[i];
    __syncthreads();

    int c = blockIdx.x;
    const float* gw = g_w + c * WEN;
    float acc = 0.f;
    for (int o = threadIdx.x; o < WEN; o += 256)
        acc = fmaf(gw[o], sq[o], acc);

    __shared__ float red[256];
    red[threadIdx.x] = acc;
    __syncthreads();
    for (int s = 128; s > 0; s >>= 1) {
        if (threadIdx.x < s) red[threadIdx.x] += red[threadIdx.x + s];
        __syncthreads();
    }
    if (threadIdx.x == 0)
        row[c] = gamma[0] * (g_b[c] + red[0]);
}

// K6: out[i*256 + c] = row[c] for all 1024 rows (fp32 output)
__global__ void k_bcast(const float* __restrict__ row, float* __restrict__ out,
                        int out_size) {
    __shared__ float sr[256];
    sr[threadIdx.x] = row[threadIdx.x];
    __syncthreads();
    int gid = blockIdx.x * 256 + threadIdx.x;     // gid & 255 == threadIdx.x == c
    if (gid < out_size) out[gid] = sr[threadIdx.x];
}

extern "C" void kernel_launch(void* const* d_in, const int* in_sizes, int n_in,
                              void* d_out, int out_size, void* d_ws, size_t ws_size,
                              hipStream_t stream) {
    // setup order: x, y, g_w, g_b, phi_w, phi_b, theta_w, theta_b, concat_w, gamma
    // dead inputs: x, theta_w, theta_b (softmax shift-invariance), phi_b (ditto)
    const float* y        = (const float*)d_in[1];
    const float* g_w      = (const float*)d_in[2];
    const float* g_b      = (const float*)d_in[3];
    const float* phi_w    = (const float*)d_in[4];
    const float* concat_w = (const float*)d_in[8];
    const float* gamma    = (const float*)d_in[9];
    float* out = (float*)d_out;

    float* ws    = (float*)d_ws;
    float* we    = ws;                 // 2304
    float* sphi  = we + WEN;           // 16384
    float* p     = sphi + NPIX;        // 16384
    float* q     = p + NPIX;           // 2304
    float* row   = q + WEN;            // 256
    (void)in_sizes; (void)n_in; (void)ws_size;

    int nb_out = (out_size + 255) / 256;   // 1024

    hipLaunchKernelGGL(k_eff_phi, dim3(9 + NPIX / 256 / 1), dim3(256),  0, stream, phi_w, concat_w, we, sphi); // wait: 9+64 blocks
    hipLaunchKernelGGL(k_sphi,    dim3(64 * NCHG), dim3(256),  0, stream, y, we, sphi);
    hipLaunchKernelGGL(k_softmax, dim3(1),         dim3(1024), 0, stream, sphi, p);
    hipLaunchKernelGGL(k_q,       dim3(CY),        dim3(256),  0, stream, y, p, q);
    hipLaunchKernelGGL(k_row,     dim3(CY),        dim3(256),  0, stream, g_w, g_b, gamma, q, row);
    hipLaunchKernelGGL(k_bcast,   dim3(nb_out),    dim3(256),  0, stream, row, out, out_size);
}

// Round 3
// 147.593 us; speedup vs baseline: 1.4985x; 1.4985x over previous
//
#include <hip/hip_runtime.h>

// N=1024, Cin=1024, Cy=256, H=W=128, inter=256 -- all tensors fp32
#define HWDIM 128
#define NPIX  (HWDIM * HWDIM)   // 16384
#define CY    256
#define INTER 256
#define KTAPS 9
#define WEN   (CY * KTAPS)      // 2304
#define CHG   16                // channels per group in k_sphi
#define NCHG  (CY / CHG)        // 16
#define NPART 64                // softmax partial blocks

// ---------------------------------------------------------------------------
// Algebra: softmax(s_theta[:,None] + s_phi[None,:], axis=1) -> s_theta cancels
// (constant along axis 1) so x/theta_* are dead; phi bias is a uniform shift,
// also cancels. z rows are all identical: z = gamma*(g_b + g_w . q),
// q[cy,t] = sum_hw p[h,w]*ypad[cy,...],  p = softmax(conv1(y, we)),
// we[cy,t] = sum_c wp[c]*phi_w[c,cy,t].
// ---------------------------------------------------------------------------

__device__ __forceinline__ float wave_red_sum(float v) {
    #pragma unroll
    for (int s = 32; s > 0; s >>= 1) v += __shfl_down(v, s, 64);
    return v;
}
__device__ __forceinline__ float wave_red_max(float v) {
    #pragma unroll
    for (int s = 32; s > 0; s >>= 1) v = fmaxf(v, __shfl_down(v, s, 64));
    return v;
}

// ---------------------------------------------------------------------------
// K1: blocks [0,36)    we[o] = sum_c wp[c]*phi_w[c,o]  (64 o per block, 4-way c split)
//     blocks [36,100)  zero sphi
//     blocks [100,109) zero q
// ---------------------------------------------------------------------------
__global__ void k1_prep(const float* __restrict__ phi_w,
                        const float* __restrict__ concat_w,
                        float* __restrict__ we,
                        float* __restrict__ sphi,
                        float* __restrict__ q) {
    int b = blockIdx.x, t = threadIdx.x;
    if (b >= 100) { q[(b - 100) * 256 + t] = 0.f; return; }
    if (b >= 36)  { sphi[(b - 36) * 256 + t] = 0.f; return; }

    int o_base = b * 64;
    int o_l = t & 63, cg = t >> 6;              // 4 c-groups of 64
    const float* pw = phi_w + o_base + o_l;
    float acc = 0.f;
    #pragma unroll 8
    for (int c = cg * 64; c < cg * 64 + 64; ++c)
        acc = fmaf(concat_w[INTER + c], pw[c * WEN], acc);

    __shared__ float red[256];
    red[t] = acc;
    __syncthreads();
    if (t < 64)
        we[o_base + t] = red[t] + red[t + 64] + red[t + 128] + red[t + 192];
}

// ---------------------------------------------------------------------------
// K2: sphi += 16-channel partial conv. grid: 16 cg x 32 rg (4 rows) = 512
// LDS: y tile [16ch][6 rows][130 cols] zero-padded + we slice
// ---------------------------------------------------------------------------
__global__ void k2_sphi(const float* __restrict__ y,
                        const float* __restrict__ we,
                        float* __restrict__ sphi) {
    __shared__ float sy[CHG * 6 * 130];   // 48.75 KB
    __shared__ float swe[CHG * KTAPS];
    int cg = blockIdx.x >> 5;             // 0..15
    int rg = blockIdx.x & 31;             // 0..31, rows rg*4 .. rg*4+3
    int t = threadIdx.x;

    if (t < CHG * KTAPS) swe[t] = we[cg * CHG * KTAPS + t];

    const int TILE = CHG * 6 * 130;       // 12480
    for (int i = t; i < TILE; i += 256) {
        int ch  = i / 780;                // 6*130
        int rem = i - ch * 780;
        int r   = rem / 130;
        int col = rem - r * 130;
        int gr = rg * 4 + r - 1;
        int gc = col - 1;
        float v = 0.f;
        if ((unsigned)gr < HWDIM && (unsigned)gc < HWDIM)
            v = y[(cg * CHG + ch) * NPIX + gr * HWDIM + gc];
        sy[i] = v;
    }
    __syncthreads();

    for (int pp = t; pp < 512; pp += 256) {
        int r = pp >> 7, c = pp & 127;
        float acc = 0.f;
        for (int ch = 0; ch < CHG; ++ch) {
            const float* yb = sy + ch * 780 + r * 130 + c;  // [r+dh+1][c+dw+1] rel
            const float* wk = swe + ch * KTAPS;
            #pragma unroll
            for (int dh = 0; dh < 3; ++dh)
                #pragma unroll
                for (int dw = 0; dw < 3; ++dw)
                    acc = fmaf(wk[dh * 3 + dw], yb[dh * 130 + dw], acc);
        }
        atomicAdd(&sphi[(rg * 4 + r) * HWDIM + c], acc);
    }
}

// ---------------------------------------------------------------------------
// K3: softmax partials. 64 blocks x 256: partials[2b]=max, [2b+1]=sum exp(x-max)
// ---------------------------------------------------------------------------
__global__ void k3_partials(const float* __restrict__ sphi,
                            float* __restrict__ partials) {
    __shared__ float s4[4];
    __shared__ float sM;
    int t = threadIdx.x, wid = t >> 6, lane = t & 63;
    float x = sphi[blockIdx.x * 256 + t];

    float m = wave_red_max(x);
    if (lane == 0) s4[wid] = m;
    __syncthreads();
    if (t == 0) sM = fmaxf(fmaxf(s4[0], s4[1]), fmaxf(s4[2], s4[3]));
    __syncthreads();
    float M = sM;

    float e = expf(x - M);
    float s = wave_red_sum(e);
    if (lane == 0) s4[wid] = s;
    __syncthreads();
    if (t == 0) {
        partials[2 * blockIdx.x]     = M;
        partials[2 * blockIdx.x + 1] = s4[0] + s4[1] + s4[2] + s4[3];
    }
}

// ---------------------------------------------------------------------------
// K4: q[cy,t] += sum over 32-row slice.  grid: 4 rg x 256 cy = 1024 blocks.
// Merges softmax partials in-block, stages padded p tile (34x130) in LDS.
// ---------------------------------------------------------------------------
__global__ void k4_q(const float* __restrict__ y,
                     const float* __restrict__ sphi,
                     const float* __restrict__ partials,
                     float* __restrict__ q) {
    __shared__ float sp[34 * 130];        // 17.3 KB padded p tile
    __shared__ float sred[64], sMS[2];
    int cy = blockIdx.x & 255;
    int rg = blockIdx.x >> 8;             // rows rg*32 .. rg*32+31
    int t = threadIdx.x;

    // merge the 64 softmax partials -> M, S
    float mt = -1e30f, st = 0.f;
    if (t < NPART) { mt = partials[2 * t]; st = partials[2 * t + 1]; }
    if (t < NPART) sred[t] = mt;
    __syncthreads();
    #pragma unroll
    for (int s = 32; s > 0; s >>= 1) {
        if (t < s) sred[t] = fmaxf(sred[t], sred[t + s]);
        __syncthreads();
    }
    float M = sred[0];
    __syncthreads();
    if (t < NPART) sred[t] = st * expf(mt - M);
    __syncthreads();
    #pragma unroll
    for (int s = 32; s > 0; s >>= 1) {
        if (t < s) sred[t] += sred[t + s];
        __syncthreads();
    }
    if (t == 0) { sMS[0] = M; sMS[1] = 1.f / sred[0]; }
    __syncthreads();
    float invS = sMS[1]; M = sMS[0];

    // stage p tile: sp[r][c] = p[rg*32 + r - 1][c - 1], zero-padded
    for (int i = t; i < 34 * 130; i += 256) {
        int r = i / 130, col = i - r * 130;
        int gr = rg * 32 + r - 1, gc = col - 1;
        float v = 0.f;
        if ((unsigned)gr < HWDIM && (unsigned)gc < HWDIM)
            v = expf(sphi[gr * HWDIM + gc] - M) * invS;
        sp[i] = v;
    }
    __syncthreads();

    // accumulate: thread (vg = t>>7, c = t&127), 4 loops x 4 vertical pixels
    const float* yc = y + cy * NPIX;
    float acc[KTAPS];
    #pragma unroll
    for (int k = 0; k < KTAPS; ++k) acc[k] = 0.f;
    int c = t & 127, vg = t >> 7;

    for (int j = 0; j < 4; ++j) {
        int lr0 = vg * 4 + j * 8;         // local row base (0..28)
        float pv[6][3];
        #pragma unroll
        for (int u = 0; u < 6; ++u)
            #pragma unroll
            for (int v = 0; v < 3; ++v)
                pv[u][v] = sp[(lr0 + u) * 130 + c + v];
        #pragma unroll
        for (int dr = 0; dr < 4; ++dr) {
            float yv = yc[(rg * 32 + lr0 + dr) * HWDIM + c];
            #pragma unroll
            for (int kh = 0; kh < 3; ++kh)
                #pragma unroll
                for (int kw = 0; kw < 3; ++kw)
                    acc[kh * 3 + kw] = fmaf(pv[dr + 2 - kh][2 - kw], yv,
                                            acc[kh * 3 + kw]);
        }
    }

    // wave reduce 9 accs, combine 4 waves via LDS, atomicAdd
    int wid = t >> 6, lane = t & 63;
    __shared__ float sq[4][KTAPS];
    #pragma unroll
    for (int k = 0; k < KTAPS; ++k) {
        float v = wave_red_sum(acc[k]);
        if (lane == 0) sq[wid][k] = v;
    }
    __syncthreads();
    if (t < KTAPS)
        atomicAdd(&q[cy * KTAPS + t],
                  sq[0][t] + sq[1][t] + sq[2][t] + sq[3][t]);
}

// ---------------------------------------------------------------------------
// K5: row[c] = gamma*(g_b[c] + g_w[c,:] . q)   256 blocks x 256
// ---------------------------------------------------------------------------
__global__ void k5_row(const float* __restrict__ g_w,
                       const float* __restrict__ g_b,
                       const float* __restrict__ gamma,
                       const float* __restrict__ q,
                       float* __restrict__ row) {
    __shared__ float sq[WEN];
    __shared__ float s4[4];
    int t = threadIdx.x, c = blockIdx.x;
    for (int i = t; i < WEN; i += 256) sq[i] = q[i];
    __syncthreads();

    const float* gw = g_w + c * WEN;
    float acc = 0.f;
    for (int o = t; o < WEN; o += 256) acc = fmaf(gw[o], sq[o], acc);
    float v = wave_red_sum(acc);
    int wid = t >> 6, lane = t & 63;
    if (lane == 0) s4[wid] = v;
    __syncthreads();
    if (t == 0) row[c] = gamma[0] * (g_b[c] + s4[0] + s4[1] + s4[2] + s4[3]);
}

// K6: broadcast row to 1024 output rows
__global__ void k6_bcast(const float* __restrict__ row, float* __restrict__ out,
                         int out_size) {
    __shared__ float sr[256];
    sr[threadIdx.x] = row[threadIdx.x];
    __syncthreads();
    int gid = blockIdx.x * 256 + threadIdx.x;
    if (gid < out_size) out[gid] = sr[threadIdx.x];
}

extern "C" void kernel_launch(void* const* d_in, const int* in_sizes, int n_in,
                              void* d_out, int out_size, void* d_ws, size_t ws_size,
                              hipStream_t stream) {
    // inputs: x, y, g_w, g_b, phi_w, phi_b, theta_w, theta_b, concat_w, gamma
    const float* y        = (const float*)d_in[1];
    const float* g_w      = (const float*)d_in[2];
    const float* g_b      = (const float*)d_in[3];
    const float* phi_w    = (const float*)d_in[4];
    const float* concat_w = (const float*)d_in[8];
    const float* gamma    = (const float*)d_in[9];
    float* out = (float*)d_out;

    float* ws       = (float*)d_ws;
    float* we       = ws;                  // 2304
    float* sphi     = we + WEN;            // 16384
    float* partials = sphi + NPIX;         // 128
    float* q        = partials + 2 * NPART;// 2304
    float* row      = q + WEN;             // 256
    (void)in_sizes; (void)n_in; (void)ws_size;

    hipLaunchKernelGGL(k1_prep,     dim3(109),  dim3(256), 0, stream, phi_w, concat_w, we, sphi, q);
    hipLaunchKernelGGL(k2_sphi,     dim3(512),  dim3(256), 0, stream, y, we, sphi);
    hipLaunchKernelGGL(k3_partials, dim3(NPART),dim3(256), 0, stream, sphi, partials);
    hipLaunchKernelGGL(k4_q,        dim3(1024), dim3(256), 0, stream, y, sphi, partials, q);
    hipLaunchKernelGGL(k5_row,      dim3(CY),   dim3(256), 0, stream, g_w, g_b, gamma, q, row);
    hipLaunchKernelGGL(k6_bcast,    dim3((out_size + 255) / 256), dim3(256), 0, stream, row, out, out_size);
}

// Round 4
// 121.063 us; speedup vs baseline: 1.8269x; 1.2191x over previous
//
#include <hip/hip_runtime.h>

// N=1024, Cin=1024, Cy=256, H=W=128, inter=256 -- all fp32
#define HWDIM 128
#define NPIX  (HWDIM * HWDIM)   // 16384
#define CY    256
#define INTER 256
#define KTAPS 9
#define WEN   (CY * KTAPS)      // 2304
#define NPART 64                // softmax partial blocks (k2b grid)
#define NW1   8                 // we_part partial count (k1 c-split)
#define NRG   4                 // k4 row-group split

// ---------------------------------------------------------------------------
// Algebra: softmax over axis 1 cancels s_theta (constant along that axis) and
// the uniform phi-bias shift -> x, theta_*, phi_b dead. All 1024 output rows
// identical: z = gamma*(g_b + g_w . q).
//   we[cy,t] = sum_c wp[c]*phi_w[c,cy,t]
//   A_t[pix] = sum_cy we[cy,t]*y[cy,pix]          (tap-first: NO halo)
//   sphi[h,w] = sum_t A_t[h+kh-1,w+kw-1]          (tiny shifted gather)
//   p = softmax(sphi);  q[cy,t] = sum_hw p[h-kh+1,w-kw+1]*y[cy,h,w]
// ---------------------------------------------------------------------------

__device__ __forceinline__ float wave_red_sum(float v) {
    #pragma unroll
    for (int s = 32; s > 0; s >>= 1) v += __shfl_down(v, s, 64);
    return v;
}
__device__ __forceinline__ float wave_red_max(float v) {
    #pragma unroll
    for (int s = 32; s > 0; s >>= 1) v = fmaxf(v, __shfl_down(v, s, 64));
    return v;
}

// K1: we_part[cg][o] = sum_{c in cg-slice of 32} wp[c]*phi_w[c,o]
// grid 72 = 9 og x 8 cg; block 256; o = og*256+t (coalesced rows of phi_w)
__global__ void k1_wepart(const float* __restrict__ phi_w,
                          const float* __restrict__ concat_w,
                          float* __restrict__ we_part) {
    int b = blockIdx.x, t = threadIdx.x;
    int og = b >> 3, cg = b & 7;
    int o = og * 256 + t;
    const float* pw = phi_w + o;
    float acc = 0.f;
    #pragma unroll 8
    for (int c = cg * 32; c < cg * 32 + 32; ++c)
        acc = fmaf(concat_w[INTER + c], pw[c * WEN], acc);
    we_part[cg * WEN + o] = acc;
}

// K2a: A_part[cg][k][pix] = sum_{ch in cg} we[cg*CPG+ch, k] * y[...]
// grid 64*NCS blocks x 256; streams y once, coalesced; no halo, no atomics.
template <int CPG>   // channels per group
__global__ void k2a_taps(const float* __restrict__ y,
                         const float* __restrict__ we_part,
                         float* __restrict__ A_part) {
    __shared__ float swe[CPG * KTAPS];
    int t = threadIdx.x;
    int pg = blockIdx.x & 63;
    int cg = blockIdx.x >> 6;

    // merge the 8 we partials for this block's channel slice
    for (int i = t; i < CPG * KTAPS; i += 256) {
        float s = 0.f;
        #pragma unroll
        for (int p = 0; p < NW1; ++p)
            s += we_part[p * WEN + cg * CPG * KTAPS + i];
        swe[i] = s;
    }
    __syncthreads();

    int pix = pg * 256 + t;
    float acc[KTAPS];
    #pragma unroll
    for (int k = 0; k < KTAPS; ++k) acc[k] = 0.f;

    const float* yp = y + (size_t)cg * CPG * NPIX + pix;
    #pragma unroll 4
    for (int ch = 0; ch < CPG; ++ch) {
        float yv = yp[ch * NPIX];
        const float* wk = swe + ch * KTAPS;   // wave-uniform LDS broadcast
        #pragma unroll
        for (int k = 0; k < KTAPS; ++k)
            acc[k] = fmaf(wk[k], yv, acc[k]);
    }
    #pragma unroll
    for (int k = 0; k < KTAPS; ++k)
        A_part[(size_t)(cg * KTAPS + k) * NPIX + pix] = acc[k];
}

// K2b: sphi[pix] = sum_{cg,k} A_part[cg][k][shifted pix]; also per-block
// softmax partials (max, sum exp). grid NPART=64 x 256.
template <int NCS>
__global__ void k2b_sphi(const float* __restrict__ A_part,
                         float* __restrict__ sphi,
                         float* __restrict__ partials) {
    __shared__ float s4[4];
    __shared__ float sM;
    int t = threadIdx.x, wid = t >> 6, lane = t & 63;
    int pix = blockIdx.x * 256 + t;
    int h = pix >> 7, w = pix & 127;

    float acc = 0.f;
    #pragma unroll
    for (int kh = 0; kh < 3; ++kh) {
        int hh = h + kh - 1;
        if ((unsigned)hh >= (unsigned)HWDIM) continue;
        #pragma unroll
        for (int kw = 0; kw < 3; ++kw) {
            int ww = w + kw - 1;
            if ((unsigned)ww >= (unsigned)HWDIM) continue;
            int idx = hh * HWDIM + ww;
            int k = kh * 3 + kw;
            #pragma unroll
            for (int cg = 0; cg < NCS; ++cg)
                acc += A_part[(size_t)(cg * KTAPS + k) * NPIX + idx];
        }
    }
    sphi[pix] = acc;

    float m = wave_red_max(acc);
    if (lane == 0) s4[wid] = m;
    __syncthreads();
    if (t == 0) sM = fmaxf(fmaxf(s4[0], s4[1]), fmaxf(s4[2], s4[3]));
    __syncthreads();
    float M = sM;
    float e = expf(acc - M);
    float s = wave_red_sum(e);
    if (lane == 0) s4[wid] = s;
    __syncthreads();
    if (t == 0) {
        partials[2 * blockIdx.x]     = M;
        partials[2 * blockIdx.x + 1] = s4[0] + s4[1] + s4[2] + s4[3];
    }
}

// K3b: merge 64 partials -> MS = {M, 1/S}. 1 block x 64 threads (one wave).
__global__ void k3b_merge(const float* __restrict__ partials,
                          float* __restrict__ MS) {
    int t = threadIdx.x;
    float m = partials[2 * t], s = partials[2 * t + 1];
    float mr = wave_red_max(m);
    float M = __shfl(mr, 0, 64);
    float sv = s * expf(m - M);
    float S = wave_red_sum(sv);
    if (t == 0) { MS[0] = M; MS[1] = 1.f / S; }
}

// K4: q_part[rg][cy*9+t] over a 32-row slice. grid 4 rg x 256 cy = 1024.
__global__ void k4_q(const float* __restrict__ y,
                     const float* __restrict__ sphi,
                     const float* __restrict__ MS,
                     float* __restrict__ q_part) {
    __shared__ float sp[34 * 130];        // padded p tile, 17.7 KB
    __shared__ float sq4[4][KTAPS];
    int cy = blockIdx.x & 255;
    int rg = blockIdx.x >> 8;
    int t = threadIdx.x;

    float M = MS[0], invS = MS[1];

    // stage p tile: sp[r][col] = p[rg*32 + r - 1][col - 1], zero-padded
    for (int i = t; i < 34 * 130; i += 256) {
        int r = i / 130, col = i - r * 130;
        int gr = rg * 32 + r - 1, gc = col - 1;
        float v = 0.f;
        if ((unsigned)gr < HWDIM && (unsigned)gc < HWDIM)
            v = expf(sphi[gr * HWDIM + gc] - M) * invS;
        sp[i] = v;
    }
    __syncthreads();

    const float* yc = y + (size_t)cy * NPIX;
    float acc[KTAPS];
    #pragma unroll
    for (int k = 0; k < KTAPS; ++k) acc[k] = 0.f;
    int c = t & 127, vg = t >> 7;

    for (int j = 0; j < 4; ++j) {
        int lr0 = vg * 4 + j * 8;         // local row base (0..28)
        float pv[6][3];
        #pragma unroll
        for (int u = 0; u < 6; ++u)
            #pragma unroll
            for (int v = 0; v < 3; ++v)
                pv[u][v] = sp[(lr0 + u) * 130 + c + v];
        #pragma unroll
        for (int dr = 0; dr < 4; ++dr) {
            float yv = yc[(rg * 32 + lr0 + dr) * HWDIM + c];
            #pragma unroll
            for (int kh = 0; kh < 3; ++kh)
                #pragma unroll
                for (int kw = 0; kw < 3; ++kw)
                    acc[kh * 3 + kw] = fmaf(pv[dr + 2 - kh][2 - kw], yv,
                                            acc[kh * 3 + kw]);
        }
    }

    int wid = t >> 6, lane = t & 63;
    #pragma unroll
    for (int k = 0; k < KTAPS; ++k) {
        float v = wave_red_sum(acc[k]);
        if (lane == 0) sq4[wid][k] = v;
    }
    __syncthreads();
    if (t < KTAPS)
        q_part[rg * WEN + cy * KTAPS + t] =
            sq4[0][t] + sq4[1][t] + sq4[2][t] + sq4[3][t];
}

// K5: row[c] = gamma*(g_b[c] + g_w[c,:] . q)  (q = sum of 4 partials)
__global__ void k5_row(const float* __restrict__ g_w,
                       const float* __restrict__ g_b,
                       const float* __restrict__ gamma,
                       const float* __restrict__ q_part,
                       float* __restrict__ row) {
    __shared__ float sq[WEN];
    __shared__ float s4[4];
    int t = threadIdx.x, c = blockIdx.x;
    for (int i = t; i < WEN; i += 256) {
        float s = 0.f;
        #pragma unroll
        for (int rg = 0; rg < NRG; ++rg) s += q_part[rg * WEN + i];
        sq[i] = s;
    }
    __syncthreads();

    const float* gw = g_w + (size_t)c * WEN;
    float acc = 0.f;
    for (int o = t; o < WEN; o += 256) acc = fmaf(gw[o], sq[o], acc);
    float v = wave_red_sum(acc);
    int wid = t >> 6, lane = t & 63;
    if (lane == 0) s4[wid] = v;
    __syncthreads();
    if (t == 0) row[c] = gamma[0] * (g_b[c] + s4[0] + s4[1] + s4[2] + s4[3]);
}

// K6: broadcast row to all 1024 output rows
__global__ void k6_bcast(const float* __restrict__ row, float* __restrict__ out,
                         int out_size) {
    __shared__ float sr[256];
    sr[threadIdx.x] = row[threadIdx.x];
    __syncthreads();
    int gid = blockIdx.x * 256 + threadIdx.x;
    if (gid < out_size) out[gid] = sr[threadIdx.x];
}

extern "C" void kernel_launch(void* const* d_in, const int* in_sizes, int n_in,
                              void* d_out, int out_size, void* d_ws, size_t ws_size,
                              hipStream_t stream) {
    // inputs: x, y, g_w, g_b, phi_w, phi_b, theta_w, theta_b, concat_w, gamma
    const float* y        = (const float*)d_in[1];
    const float* g_w      = (const float*)d_in[2];
    const float* g_b      = (const float*)d_in[3];
    const float* phi_w    = (const float*)d_in[4];
    const float* concat_w = (const float*)d_in[8];
    const float* gamma    = (const float*)d_in[9];
    float* out = (float*)d_out;

    // channel-split for the A buffers: 8-way if workspace allows, else 2-way
    const bool big = ws_size >= (size_t)(6u << 20);
    const int  ncs = big ? 8 : 2;

    float* ws       = (float*)d_ws;
    float* we_part  = ws;                            // 8*2304
    float* A_part   = we_part + NW1 * WEN;           // ncs*9*16384
    float* sphi     = A_part + (size_t)ncs * KTAPS * NPIX;  // 16384
    float* partials = sphi + NPIX;                   // 128
    float* MS       = partials + 2 * NPART;          // 2 (+pad)
    float* q_part   = MS + 16;                       // 4*2304
    float* row      = q_part + NRG * WEN;            // 256
    (void)in_sizes; (void)n_in;

    hipLaunchKernelGGL(k1_wepart, dim3(72), dim3(256), 0, stream,
                       phi_w, concat_w, we_part);
    if (big)
        hipLaunchKernelGGL(k2a_taps<32>,  dim3(64 * 8), dim3(256), 0, stream,
                           y, we_part, A_part);
    else
        hipLaunchKernelGGL(k2a_taps<128>, dim3(64 * 2), dim3(256), 0, stream,
                           y, we_part, A_part);
    if (big)
        hipLaunchKernelGGL(k2b_sphi<8>, dim3(NPART), dim3(256), 0, stream,
                           A_part, sphi, partials);
    else
        hipLaunchKernelGGL(k2b_sphi<2>, dim3(NPART), dim3(256), 0, stream,
                           A_part, sphi, partials);
    hipLaunchKernelGGL(k3b_merge, dim3(1), dim3(64), 0, stream, partials, MS);
    hipLaunchKernelGGL(k4_q, dim3(NRG * CY), dim3(256), 0, stream,
                       y, sphi, MS, q_part);
    hipLaunchKernelGGL(k5_row, dim3(CY), dim3(256), 0, stream,
                       g_w, g_b, gamma, q_part, row);
    hipLaunchKernelGGL(k6_bcast, dim3((out_size + 255) / 256), dim3(256), 0,
                       stream, row, out, out_size);
}

// Round 5
// 117.061 us; speedup vs baseline: 1.8893x; 1.0342x over previous
//
#include <hip/hip_runtime.h>

// N=1024, Cin=1024, Cy=256, H=W=128, inter=256 -- all fp32
#define HWDIM 128
#define NPIX  (HWDIM * HWDIM)   // 16384
#define CY    256
#define INTER 256
#define KTAPS 9
#define WEN   (CY * KTAPS)      // 2304
#define NW1   32                // k1 c-split (we partials)
#define NCS   8                 // A channel groups
#define CPG   32                // channels per A group
#define NPART2 256              // softmax partial pairs (k2b grid)
#define NRG   4                 // k4 row-group split

// ---------------------------------------------------------------------------
// Algebra: softmax over axis 1 cancels s_theta (constant along that axis) and
// the uniform phi-bias shift -> x, theta_*, phi_b dead. All 1024 output rows
// identical: z = gamma*(g_b + g_w . q).
//   we[cy,t] = sum_c wp[c]*phi_w[c,cy,t]
//   A[cg,t,pix] = sum_{cy in cg} we[cy,t]*y[cy,pix]     (tap-first: NO halo)
//   sphi[h,w] = sum_{cg,t} A[cg,t, shifted(h,w)]        (tiny L2 gather)
//   p = softmax(sphi);  q[cy,t] = sum_hw p[h-kh+1,w-kw+1]*y[cy,h,w]
// NOTE (profiling): harness re-poison of the 256MB d_ws (fillBufferAligned,
// ~44us @ 6TB/s) + input restores are INSIDE dur_us -> ~58us fixed floor.
// ---------------------------------------------------------------------------

__device__ __forceinline__ float wave_red_sum(float v) {
    #pragma unroll
    for (int s = 32; s > 0; s >>= 1) v += __shfl_down(v, s, 64);
    return v;
}
__device__ __forceinline__ float wave_red_max(float v) {
    #pragma unroll
    for (int s = 32; s > 0; s >>= 1) v = fmaxf(v, __shfl_down(v, s, 64));
    return v;
}

// K1: we_part[cg][o] = sum_{c in 8-slice} wp[c]*phi_w[c,o]
// grid 288 = 32 cg x 9 og; threads span o (coalesced phi_w rows)
__global__ void k1_wepart(const float* __restrict__ phi_w,
                          const float* __restrict__ concat_w,
                          float* __restrict__ we_part) {
    int b = blockIdx.x, t = threadIdx.x;
    int cg = b / 9, og = b - cg * 9;
    int o = og * 256 + t;
    const float* pw = phi_w + o;
    float acc = 0.f;
    #pragma unroll
    for (int j = 0; j < 8; ++j) {
        int c = cg * 8 + j;
        acc = fmaf(concat_w[INTER + c], pw[c * WEN], acc);
    }
    we_part[cg * WEN + o] = acc;
}

// K2a: A[cg][k][pix] = sum_{ch in cg} we[cg*CPG+ch, k] * y[ch,pix]
// grid 512 = 8 cg x 64 pg; streams y coalesced once.
__global__ void k2a_taps(const float* __restrict__ y,
                         const float* __restrict__ we_part,
                         float* __restrict__ A) {
    __shared__ float swe[CPG * KTAPS];      // 288
    int t = threadIdx.x;
    int pg = blockIdx.x & 63;
    int cg = blockIdx.x >> 6;

    for (int i = t; i < CPG * KTAPS; i += 256) {
        float s = 0.f;
        #pragma unroll
        for (int p = 0; p < NW1; ++p)
            s += we_part[p * WEN + cg * CPG * KTAPS + i];
        swe[i] = s;
    }
    __syncthreads();

    int pix = pg * 256 + t;
    float acc[KTAPS];
    #pragma unroll
    for (int k = 0; k < KTAPS; ++k) acc[k] = 0.f;

    const float* yp = y + (size_t)cg * CPG * NPIX + pix;
    #pragma unroll 4
    for (int ch = 0; ch < CPG; ++ch) {
        float yv = yp[ch * NPIX];
        const float* wk = swe + ch * KTAPS;   // wave-uniform LDS broadcast
        #pragma unroll
        for (int k = 0; k < KTAPS; ++k)
            acc[k] = fmaf(wk[k], yv, acc[k]);
    }
    #pragma unroll
    for (int k = 0; k < KTAPS; ++k)
        A[(size_t)(cg * KTAPS + k) * NPIX + pix] = acc[k];
}

// K2b: sphi[pix] = sum_{cg,k} A[cg][k][shifted]; per-block softmax partials.
// grid 256; block covers 64 pixels x 4 term-groups (2 cg x 9 taps each).
__global__ void k2b_sphi(const float* __restrict__ A,
                         float* __restrict__ sphi,
                         float* __restrict__ partials) {
    __shared__ float sred[256];
    int t = threadIdx.x;
    int tg = t >> 6, pl = t & 63;
    int pix = blockIdx.x * 64 + pl;
    int h = pix >> 7, w = pix & 127;

    int idx[KTAPS]; bool val[KTAPS];
    #pragma unroll
    for (int kh = 0; kh < 3; ++kh)
        #pragma unroll
        for (int kw = 0; kw < 3; ++kw) {
            int hh = h + kh - 1, ww = w + kw - 1;
            int k = kh * 3 + kw;
            val[k] = ((unsigned)hh < HWDIM) & ((unsigned)ww < HWDIM);
            idx[k] = hh * HWDIM + ww;
        }

    float acc = 0.f;
    #pragma unroll
    for (int cc = 0; cc < 2; ++cc) {
        const float* Ab = A + (size_t)(tg * 2 + cc) * KTAPS * NPIX;
        #pragma unroll
        for (int k = 0; k < KTAPS; ++k)
            if (val[k]) acc += Ab[(size_t)k * NPIX + idx[k]];
    }
    sred[t] = acc;
    __syncthreads();

    if (t < 64) {
        float v = sred[t] + sred[t + 64] + sred[t + 128] + sred[t + 192];
        sphi[blockIdx.x * 64 + t] = v;
        float m = wave_red_max(v);
        float M = __shfl(m, 0, 64);
        float e = expf(v - M);
        float s = wave_red_sum(e);
        if (t == 0) {
            partials[2 * blockIdx.x]     = M;
            partials[2 * blockIdx.x + 1] = s;
        }
    }
}

// K4: q_part[rg][cy*9+t] over a 32-row slice; merges the 256 softmax
// partials in-block. grid 1024 = 4 rg x 256 cy.
__global__ void k4_q(const float* __restrict__ y,
                     const float* __restrict__ sphi,
                     const float* __restrict__ partials,
                     float* __restrict__ q_part) {
    __shared__ float sp[34 * 130];        // padded p tile, 17.7 KB
    __shared__ float s4m[4], s4s[4];
    __shared__ float sq4[4][KTAPS];
    int cy = blockIdx.x & 255;
    int rg = blockIdx.x >> 8;
    int t = threadIdx.x;
    int wid = t >> 6, lane = t & 63;

    // merge 256 partial pairs -> M, invS (thread t owns pair t)
    float m = partials[2 * t], s = partials[2 * t + 1];
    float wm = wave_red_max(m);
    if (lane == 0) s4m[wid] = wm;
    __syncthreads();
    float M = fmaxf(fmaxf(s4m[0], s4m[1]), fmaxf(s4m[2], s4m[3]));
    float sv = s * expf(m - M);
    float wsum = wave_red_sum(sv);
    if (lane == 0) s4s[wid] = wsum;
    __syncthreads();
    float invS = 1.f / (s4s[0] + s4s[1] + s4s[2] + s4s[3]);

    // stage p tile: sp[r][col] = p[rg*32 + r - 1][col - 1], zero-padded
    for (int i = t; i < 34 * 130; i += 256) {
        int r = i / 130, col = i - r * 130;
        int gr = rg * 32 + r - 1, gc = col - 1;
        float v = 0.f;
        if ((unsigned)gr < HWDIM && (unsigned)gc < HWDIM)
            v = expf(sphi[gr * HWDIM + gc] - M) * invS;
        sp[i] = v;
    }
    __syncthreads();

    const float* yc = y + (size_t)cy * NPIX;
    float acc[KTAPS];
    #pragma unroll
    for (int k = 0; k < KTAPS; ++k) acc[k] = 0.f;
    int c = t & 127, vg = t >> 7;

    for (int j = 0; j < 4; ++j) {
        int lr0 = vg * 4 + j * 8;         // local row base (0..28)
        float pv[6][3];
        #pragma unroll
        for (int u = 0; u < 6; ++u)
            #pragma unroll
            for (int v = 0; v < 3; ++v)
                pv[u][v] = sp[(lr0 + u) * 130 + c + v];
        #pragma unroll
        for (int dr = 0; dr < 4; ++dr) {
            float yv = yc[(rg * 32 + lr0 + dr) * HWDIM + c];
            #pragma unroll
            for (int kh = 0; kh < 3; ++kh)
                #pragma unroll
                for (int kw = 0; kw < 3; ++kw)
                    acc[kh * 3 + kw] = fmaf(pv[dr + 2 - kh][2 - kw], yv,
                                            acc[kh * 3 + kw]);
        }
    }

    #pragma unroll
    for (int k = 0; k < KTAPS; ++k) {
        float v = wave_red_sum(acc[k]);
        if (lane == 0) sq4[wid][k] = v;
    }
    __syncthreads();
    if (t < KTAPS)
        q_part[rg * WEN + cy * KTAPS + t] =
            sq4[0][t] + sq4[1][t] + sq4[2][t] + sq4[3][t];
}

// K5: row_part[half][c] = g_w[c, half-slice] . q  (q merged from 4 partials)
// grid 512 = 2 half x 256 c
__global__ void k5_row(const float* __restrict__ g_w,
                       const float* __restrict__ q_part,
                       float* __restrict__ row_part) {
    __shared__ float s4[4];
    int t = threadIdx.x;
    int c = blockIdx.x & 255, half = blockIdx.x >> 8;
    int base = half * (WEN / 2);          // 1152

    const float* gw = g_w + (size_t)c * WEN;
    float acc = 0.f;
    #pragma unroll
    for (int j = 0; j < 5; ++j) {
        int o = base + j * 256 + t;
        if (o < base + WEN / 2) {
            float qv = q_part[o] + q_part[WEN + o] +
                       q_part[2 * WEN + o] + q_part[3 * WEN + o];
            acc = fmaf(gw[o], qv, acc);
        }
    }
    float v = wave_red_sum(acc);
    int wid = t >> 6, lane = t & 63;
    if (lane == 0) s4[wid] = v;
    __syncthreads();
    if (t == 0)
        row_part[half * 256 + c] = s4[0] + s4[1] + s4[2] + s4[3];
}

// K6: out[i*256+c] = gamma*(g_b[c] + row_part[0][c] + row_part[1][c])
__global__ void k6_bcast(const float* __restrict__ row_part,
                         const float* __restrict__ g_b,
                         const float* __restrict__ gamma,
                         float* __restrict__ out, int out_size) {
    __shared__ float sr[256];
    int t = threadIdx.x;
    sr[t] = gamma[0] * (g_b[t] + row_part[t] + row_part[256 + t]);
    __syncthreads();
    int gid = blockIdx.x * 256 + t;
    if (gid < out_size) out[gid] = sr[t];
}

extern "C" void kernel_launch(void* const* d_in, const int* in_sizes, int n_in,
                              void* d_out, int out_size, void* d_ws, size_t ws_size,
                              hipStream_t stream) {
    // inputs: x, y, g_w, g_b, phi_w, phi_b, theta_w, theta_b, concat_w, gamma
    const float* y        = (const float*)d_in[1];
    const float* g_w      = (const float*)d_in[2];
    const float* g_b      = (const float*)d_in[3];
    const float* phi_w    = (const float*)d_in[4];
    const float* concat_w = (const float*)d_in[8];
    const float* gamma    = (const float*)d_in[9];
    float* out = (float*)d_out;

    float* ws       = (float*)d_ws;
    float* we_part  = ws;                            // 32*2304   = 73728
    float* A        = we_part + NW1 * WEN;           // 8*9*16384 = 1179648
    float* sphi     = A + (size_t)NCS * KTAPS * NPIX;// 16384
    float* partials = sphi + NPIX;                   // 512
    float* q_part   = partials + 2 * NPART2;         // 4*2304
    float* row_part = q_part + NRG * WEN;            // 512
    (void)in_sizes; (void)n_in; (void)ws_size;

    hipLaunchKernelGGL(k1_wepart, dim3(288),      dim3(256), 0, stream,
                       phi_w, concat_w, we_part);
    hipLaunchKernelGGL(k2a_taps,  dim3(64 * NCS), dim3(256), 0, stream,
                       y, we_part, A);
    hipLaunchKernelGGL(k2b_sphi,  dim3(NPART2),   dim3(256), 0, stream,
                       A, sphi, partials);
    hipLaunchKernelGGL(k4_q,      dim3(NRG * CY), dim3(256), 0, stream,
                       y, sphi, partials, q_part);
    hipLaunchKernelGGL(k5_row,    dim3(512),      dim3(256), 0, stream,
                       g_w, q_part, row_part);
    hipLaunchKernelGGL(k6_bcast,  dim3((out_size + 255) / 256), dim3(256), 0,
                       stream, row_part, g_b, gamma, out, out_size);
}